// Round 1
// baseline (502.982 us; speedup 1.0000x reference)
//
#include <hip/hip_runtime.h>

#define B_  2
#define S_  2048
#define D_  1024
#define H_  16
#define DH_ 64

typedef _Float16 f16;
typedef f16   f16x8 __attribute__((ext_vector_type(8)));
typedef float f32x4 __attribute__((ext_vector_type(4)));

static __device__ __forceinline__ f16x8 ldsm8(const f16* p) {
    return *reinterpret_cast<const f16x8*>(p);
}

// C[M,N] = A[M,K] @ W[N,K]^T (+bias)*scale.  M=4096, N=K=1024.
// A is fp32 or f16 (template), W/bias fp32.  Out fp32 or f16.
template<int A_IS_F16, int OUT_IS_F16>
__global__ __launch_bounds__(256)
void gemm_bt(const void* __restrict__ Ap, const float* __restrict__ W,
             const float* __restrict__ bias, void* __restrict__ Cp, float scale)
{
    constexpr int K = 1024, N = 1024;
    __shared__ __align__(16) f16 As[128][40];
    __shared__ __align__(16) f16 Bs[128][40];
    const int t  = threadIdx.x;
    const int bm = blockIdx.y * 128;
    const int bn = blockIdx.x * 128;
    const int w  = t >> 6, l = t & 63;
    const int wr = w >> 1, wc = w & 1;
    const int lr = l & 15, lg = l >> 4;

    f32x4 acc[4][4];
    #pragma unroll
    for (int m = 0; m < 4; ++m)
        #pragma unroll
        for (int n = 0; n < 4; ++n)
            acc[m][n] = (f32x4){0.f, 0.f, 0.f, 0.f};

    for (int kt = 0; kt < K / 32; ++kt) {
        if (A_IS_F16) {
            const f16* A = (const f16*)Ap;
            #pragma unroll
            for (int i = 0; i < 2; ++i) {
                int idx = t + i * 256;
                int row = idx >> 2, g = idx & 3;
                *reinterpret_cast<uint4*>(&As[row][g * 8]) =
                    *reinterpret_cast<const uint4*>(A + (size_t)(bm + row) * K + kt * 32 + g * 8);
            }
        } else {
            const float* A = (const float*)Ap;
            #pragma unroll
            for (int i = 0; i < 4; ++i) {
                int idx = t + i * 256;
                int row = idx >> 3, g = idx & 7;
                float4 v = *reinterpret_cast<const float4*>(A + (size_t)(bm + row) * K + kt * 32 + g * 4);
                alignas(8) f16 hh[4] = {(f16)v.x, (f16)v.y, (f16)v.z, (f16)v.w};
                *reinterpret_cast<uint2*>(&As[row][g * 4]) = *reinterpret_cast<uint2*>(hh);
            }
        }
        #pragma unroll
        for (int i = 0; i < 4; ++i) {
            int idx = t + i * 256;
            int row = idx >> 3, g = idx & 7;
            float4 v = *reinterpret_cast<const float4*>(W + (size_t)(bn + row) * K + kt * 32 + g * 4);
            alignas(8) f16 hh[4] = {(f16)v.x, (f16)v.y, (f16)v.z, (f16)v.w};
            *reinterpret_cast<uint2*>(&Bs[row][g * 4]) = *reinterpret_cast<uint2*>(hh);
        }
        __syncthreads();

        f16x8 af[4], bfv[4];
        #pragma unroll
        for (int m = 0; m < 4; ++m) af[m]  = ldsm8(&As[wr * 64 + m * 16 + lr][lg * 8]);
        #pragma unroll
        for (int n = 0; n < 4; ++n) bfv[n] = ldsm8(&Bs[wc * 64 + n * 16 + lr][lg * 8]);
        #pragma unroll
        for (int m = 0; m < 4; ++m)
            #pragma unroll
            for (int n = 0; n < 4; ++n)
                acc[m][n] = __builtin_amdgcn_mfma_f32_16x16x32_f16(af[m], bfv[n], acc[m][n], 0, 0, 0);
        __syncthreads();
    }

    #pragma unroll
    for (int m = 0; m < 4; ++m) {
        #pragma unroll
        for (int n = 0; n < 4; ++n) {
            int col = bn + wc * 64 + n * 16 + lr;
            float bb = bias[col];
            #pragma unroll
            for (int j = 0; j < 4; ++j) {
                int row = bm + wr * 64 + m * 16 + lg * 4 + j;
                float val = (acc[m][n][j] + bb) * scale;
                if (OUT_IS_F16) ((f16*)Cp)[(size_t)row * N + col] = (f16)val;
                else            ((float*)Cp)[(size_t)row * N + col] = val;
            }
        }
    }
}

// One block per (b, h, 64-row q-tile). 256 threads = 4 waves; wave w owns rows
// [w*16, w*16+16).  Two-pass exact softmax; writes attn fp32 + ctx f16.
__global__ __launch_bounds__(256)
void attn_fused(const f16* __restrict__ qh, const f16* __restrict__ kh,
                const f16* __restrict__ vh, const int* __restrict__ kmask,
                float* __restrict__ attn_out, f16* __restrict__ ch)
{
    __shared__ __align__(16) f16 qs[64][72];
    __shared__ __align__(16) f16 ks[64][72];
    __shared__ __align__(16) f16 vt[64][72];   // vt[d][j] = v[j][d]
    __shared__ __align__(16) f16 ps[64][72];
    __shared__ float mb[S_];

    const int t  = threadIdx.x;
    const int w  = t >> 6, l = t & 63, lr = l & 15, lg = l >> 4;
    const int bid = blockIdx.x;
    const int qt = bid & 31;
    const int h  = (bid >> 5) & 15;
    const int b  = bid >> 9;
    const int q0 = qt * 64;

    for (int j = t; j < S_; j += 256)
        mb[j] = kmask[b * S_ + j] ? 0.0f : -1e18f;

    #pragma unroll
    for (int i = 0; i < 2; ++i) {
        int idx = t + i * 256;
        int row = idx >> 3, g = idx & 7;
        *reinterpret_cast<uint4*>(&qs[row][g * 8]) =
            *reinterpret_cast<const uint4*>(qh + (size_t)(b * S_ + q0 + row) * D_ + h * DH_ + g * 8);
    }
    __syncthreads();

    float m[4], lsum[4];
    #pragma unroll
    for (int j = 0; j < 4; ++j) { m[j] = -__builtin_inff(); lsum[j] = 0.f; }

    // ---- pass 1: row max + denom ----
    for (int kt = 0; kt < S_ / 64; ++kt) {
        #pragma unroll
        for (int i = 0; i < 2; ++i) {
            int idx = t + i * 256;
            int row = idx >> 3, g = idx & 7;
            *reinterpret_cast<uint4*>(&ks[row][g * 8]) =
                *reinterpret_cast<const uint4*>(kh + (size_t)(b * S_ + kt * 64 + row) * D_ + h * DH_ + g * 8);
        }
        __syncthreads();

        float sv[4][4];
        #pragma unroll
        for (int ct = 0; ct < 4; ++ct) {
            f32x4 sa = (f32x4){0.f, 0.f, 0.f, 0.f};
            #pragma unroll
            for (int ks2 = 0; ks2 < 64; ks2 += 32) {
                f16x8 a   = ldsm8(&qs[w * 16 + lr][ks2 + lg * 8]);
                f16x8 bfr = ldsm8(&ks[ct * 16 + lr][ks2 + lg * 8]);
                sa = __builtin_amdgcn_mfma_f32_16x16x32_f16(a, bfr, sa, 0, 0, 0);
            }
            float mbv = mb[kt * 64 + ct * 16 + lr];
            #pragma unroll
            for (int j = 0; j < 4; ++j) sv[ct][j] = sa[j] + mbv;
        }
        #pragma unroll
        for (int j = 0; j < 4; ++j) {
            float tm = fmaxf(fmaxf(sv[0][j], sv[1][j]), fmaxf(sv[2][j], sv[3][j]));
            #pragma unroll
            for (int off = 8; off >= 1; off >>= 1)
                tm = fmaxf(tm, __shfl_xor(tm, off, 64));
            float nm = fmaxf(m[j], tm);
            float pe = __expf(sv[0][j] - nm) + __expf(sv[1][j] - nm)
                     + __expf(sv[2][j] - nm) + __expf(sv[3][j] - nm);
            #pragma unroll
            for (int off = 8; off >= 1; off >>= 1)
                pe += __shfl_xor(pe, off, 64);
            lsum[j] = lsum[j] * __expf(m[j] - nm) + pe;
            m[j] = nm;
        }
        __syncthreads();
    }

    float invl[4];
    #pragma unroll
    for (int j = 0; j < 4; ++j) invl[j] = 1.0f / lsum[j];

    f32x4 oc[4];
    #pragma unroll
    for (int n = 0; n < 4; ++n) oc[n] = (f32x4){0.f, 0.f, 0.f, 0.f};

    // ---- pass 2: recompute, normalize, write attn, accumulate ctx ----
    for (int kt = 0; kt < S_ / 64; ++kt) {
        #pragma unroll
        for (int i = 0; i < 2; ++i) {
            int idx = t + i * 256;
            int row = idx >> 3, g = idx & 7;
            *reinterpret_cast<uint4*>(&ks[row][g * 8]) =
                *reinterpret_cast<const uint4*>(kh + (size_t)(b * S_ + kt * 64 + row) * D_ + h * DH_ + g * 8);
            uint4 vv = *reinterpret_cast<const uint4*>(vh + (size_t)(b * S_ + kt * 64 + row) * D_ + h * DH_ + g * 8);
            const f16* pe = reinterpret_cast<const f16*>(&vv);
            #pragma unroll
            for (int c = 0; c < 8; ++c) vt[g * 8 + c][row] = pe[c];
        }
        __syncthreads();

        float sv[4][4];
        #pragma unroll
        for (int ct = 0; ct < 4; ++ct) {
            f32x4 sa = (f32x4){0.f, 0.f, 0.f, 0.f};
            #pragma unroll
            for (int ks2 = 0; ks2 < 64; ks2 += 32) {
                f16x8 a   = ldsm8(&qs[w * 16 + lr][ks2 + lg * 8]);
                f16x8 bfr = ldsm8(&ks[ct * 16 + lr][ks2 + lg * 8]);
                sa = __builtin_amdgcn_mfma_f32_16x16x32_f16(a, bfr, sa, 0, 0, 0);
            }
            float mbv = mb[kt * 64 + ct * 16 + lr];
            #pragma unroll
            for (int j = 0; j < 4; ++j) sv[ct][j] = sa[j] + mbv;
        }
        #pragma unroll
        for (int ct = 0; ct < 4; ++ct) {
            #pragma unroll
            for (int j = 0; j < 4; ++j) {
                float p = __expf(sv[ct][j] - m[j]) * invl[j];   // masked -> exp(-1e18)=0 exactly
                int rowl = w * 16 + lg * 4 + j;
                int cl   = ct * 16 + lr;
                attn_out[((size_t)((b * H_ + h) * S_ + (q0 + rowl))) * S_ + kt * 64 + cl] = p;
                ps[rowl][cl] = (f16)p;
            }
        }
        __syncthreads();

        #pragma unroll
        for (int n = 0; n < 4; ++n) {
            #pragma unroll
            for (int ks2 = 0; ks2 < 64; ks2 += 32) {
                f16x8 a   = ldsm8(&ps[w * 16 + lr][ks2 + lg * 8]);
                f16x8 bfr = ldsm8(&vt[n * 16 + lr][ks2 + lg * 8]);
                oc[n] = __builtin_amdgcn_mfma_f32_16x16x32_f16(a, bfr, oc[n], 0, 0, 0);
            }
        }
        __syncthreads();
    }

    #pragma unroll
    for (int n = 0; n < 4; ++n) {
        #pragma unroll
        for (int j = 0; j < 4; ++j) {
            int row = q0 + w * 16 + lg * 4 + j;
            int d   = n * 16 + lr;
            ch[(size_t)(b * S_ + row) * D_ + h * DH_ + d] = (f16)oc[n][j];
        }
    }
}

extern "C" void kernel_launch(void* const* d_in, const int* in_sizes, int n_in,
                              void* d_out, int out_size, void* d_ws, size_t ws_size,
                              hipStream_t stream) {
    const float* query = (const float*)d_in[0];
    const float* key   = (const float*)d_in[1];
    const float* value = (const float*)d_in[2];
    const int*   kmask = (const int*)d_in[3];
    const float* Wq = (const float*)d_in[4];
    const float* bq = (const float*)d_in[5];
    const float* Wk = (const float*)d_in[6];
    const float* bk = (const float*)d_in[7];
    const float* Wv = (const float*)d_in[8];
    const float* bv = (const float*)d_in[9];
    const float* Wo = (const float*)d_in[10];
    const float* bo = (const float*)d_in[11];

    float* out  = (float*)d_out;
    float* attn = out + (size_t)B_ * S_ * D_;

    const size_t NE = (size_t)B_ * S_ * D_;   // 4,194,304 elements
    f16* qh = (f16*)d_ws;
    f16* kh = qh + NE;
    f16* vh = kh + NE;
    f16* chx = vh + NE;                        // needs 32 MB of ws total

    dim3 grid(8, 32), blk(256);
    const float qscale = 0.125f;               // 1/sqrt(DH)

    gemm_bt<0, 1><<<grid, blk, 0, stream>>>((const void*)query, Wq, bq, (void*)qh, qscale);
    gemm_bt<0, 1><<<grid, blk, 0, stream>>>((const void*)key,   Wk, bk, (void*)kh, 1.0f);
    gemm_bt<0, 1><<<grid, blk, 0, stream>>>((const void*)value, Wv, bv, (void*)vh, 1.0f);

    attn_fused<<<dim3(B_ * H_ * (S_ / 64)), blk, 0, stream>>>(qh, kh, vh, kmask, attn, chx);

    gemm_bt<1, 0><<<grid, blk, 0, stream>>>((const void*)chx, Wo, bo, (void*)out, 1.0f);
}

// Round 2
// 442.182 us; speedup vs baseline: 1.1375x; 1.1375x over previous
//
#include <hip/hip_runtime.h>

#define B_  2
#define S_  2048
#define D_  1024
#define H_  16
#define DH_ 64

typedef _Float16 f16;
typedef f16   f16x4 __attribute__((ext_vector_type(4)));
typedef f16   f16x8 __attribute__((ext_vector_type(8)));
typedef float f32x4 __attribute__((ext_vector_type(4)));

static __device__ __forceinline__ f16x8 ldsm8(const f16* p) {
    return *reinterpret_cast<const f16x8*>(p);
}

// C[M,N] = A[M,K] @ W[N,K]^T (+bias)*scale.  M=4096, N=K=1024.
// OUT: 0 = f32 row-major, 1 = f16 row-major, 2 = f16 transposed-per-head
//      (vtg[((b*16+h)*64+d)*2048 + s] = C[b*2048+s][h*64+d])
template<int A_IS_F16, int OUT>
__global__ __launch_bounds__(256)
void gemm_bt(const void* __restrict__ Ap, const float* __restrict__ W,
             const float* __restrict__ bias, void* __restrict__ Cp, float scale)
{
    constexpr int K = 1024, N = 1024;
    __shared__ __align__(16) f16 As[128][40];
    __shared__ __align__(16) f16 Bs[128][40];
    const int t  = threadIdx.x;
    const int bm = blockIdx.y * 128;
    const int bn = blockIdx.x * 128;
    const int w  = t >> 6, l = t & 63;
    const int wr = w >> 1, wc = w & 1;
    const int lr = l & 15, lg = l >> 4;

    f32x4 acc[4][4];
    #pragma unroll
    for (int m = 0; m < 4; ++m)
        #pragma unroll
        for (int n = 0; n < 4; ++n)
            acc[m][n] = (f32x4){0.f, 0.f, 0.f, 0.f};

    for (int kt = 0; kt < K / 32; ++kt) {
        if (A_IS_F16) {
            const f16* A = (const f16*)Ap;
            #pragma unroll
            for (int i = 0; i < 2; ++i) {
                int idx = t + i * 256;
                int row = idx >> 2, g = idx & 3;
                *reinterpret_cast<uint4*>(&As[row][g * 8]) =
                    *reinterpret_cast<const uint4*>(A + (size_t)(bm + row) * K + kt * 32 + g * 8);
            }
        } else {
            const float* A = (const float*)Ap;
            #pragma unroll
            for (int i = 0; i < 4; ++i) {
                int idx = t + i * 256;
                int row = idx >> 3, g = idx & 7;
                float4 v = *reinterpret_cast<const float4*>(A + (size_t)(bm + row) * K + kt * 32 + g * 4);
                alignas(8) f16 hh[4] = {(f16)v.x, (f16)v.y, (f16)v.z, (f16)v.w};
                *reinterpret_cast<uint2*>(&As[row][g * 4]) = *reinterpret_cast<uint2*>(hh);
            }
        }
        #pragma unroll
        for (int i = 0; i < 4; ++i) {
            int idx = t + i * 256;
            int row = idx >> 3, g = idx & 7;
            float4 v = *reinterpret_cast<const float4*>(W + (size_t)(bn + row) * K + kt * 32 + g * 4);
            alignas(8) f16 hh[4] = {(f16)v.x, (f16)v.y, (f16)v.z, (f16)v.w};
            *reinterpret_cast<uint2*>(&Bs[row][g * 4]) = *reinterpret_cast<uint2*>(hh);
        }
        __syncthreads();

        f16x8 af[4], bfv[4];
        #pragma unroll
        for (int m = 0; m < 4; ++m) af[m]  = ldsm8(&As[wr * 64 + m * 16 + lr][lg * 8]);
        #pragma unroll
        for (int n = 0; n < 4; ++n) bfv[n] = ldsm8(&Bs[wc * 64 + n * 16 + lr][lg * 8]);
        #pragma unroll
        for (int m = 0; m < 4; ++m)
            #pragma unroll
            for (int n = 0; n < 4; ++n)
                acc[m][n] = __builtin_amdgcn_mfma_f32_16x16x32_f16(af[m], bfv[n], acc[m][n], 0, 0, 0);
        __syncthreads();
    }

    #pragma unroll
    for (int m = 0; m < 4; ++m) {
        #pragma unroll
        for (int n = 0; n < 4; ++n) {
            int col = bn + wc * 64 + n * 16 + lr;
            float bb = bias[col];
            if (OUT == 2) {
                int row0 = bm + wr * 64 + m * 16 + lg * 4;   // 4 consecutive rows
                int b = row0 >> 11, s = row0 & 2047;
                int hh_ = col >> 6, d = col & 63;
                alignas(8) f16 hv[4];
                #pragma unroll
                for (int j = 0; j < 4; ++j)
                    hv[j] = (f16)((acc[m][n][j] + bb) * scale);
                *reinterpret_cast<uint2*>((f16*)Cp +
                    (((size_t)(b * 16 + hh_) * 64 + d) * 2048 + s)) =
                    *reinterpret_cast<uint2*>(hv);
            } else {
                #pragma unroll
                for (int j = 0; j < 4; ++j) {
                    int row = bm + wr * 64 + m * 16 + lg * 4 + j;
                    float val = (acc[m][n][j] + bb) * scale;
                    if (OUT == 1) ((f16*)Cp)[(size_t)row * N + col] = (f16)val;
                    else          ((float*)Cp)[(size_t)row * N + col] = val;
                }
            }
        }
    }
}

// One block per (b, h, 64-row q-tile). 256 threads = 4 waves.
// Two-pass, no-max softmax in exp2 domain (log2e folded into q scale).
// Pass 1: row sums only (deferred cross-lane reduce). Pass 2: recompute,
// unnormalized P -> PV MFMA + coalesced normalized attn write.
__global__ __launch_bounds__(256)
void attn_fused(const f16* __restrict__ qh, const f16* __restrict__ kh,
                const f16* __restrict__ vtg, const int* __restrict__ kmask,
                float* __restrict__ attn_out, f16* __restrict__ ch)
{
    __shared__ __align__(16) f16 qs[64][72];
    __shared__ __align__(16) f16 ks[64][72];
    __shared__ __align__(16) f16 vt[64][72];   // vt[d][k] from vtg (pre-transposed)
    __shared__ __align__(16) f16 ps[64][72];
    __shared__ float mb[S_];
    __shared__ float linv[64];

    const int t  = threadIdx.x;
    const int w  = t >> 6, l = t & 63, lr = l & 15, lg = l >> 4;

    // XCD-aware swizzle: 1024 blocks = 8 xcd * 4 bh * 32 qt; all 32 q-tiles of
    // one (b,h) land on one XCD -> K/V strip cached in a single L2.
    const int bid  = blockIdx.x;
    const int xcd  = bid & 7;
    const int slot = bid >> 3;
    const int bh   = (xcd << 2) | (slot >> 5);
    const int qt   = slot & 31;
    const int b    = bh >> 4;
    const int h    = bh & 15;
    const int q0   = qt * 64;

    for (int j = t; j < S_; j += 256)
        mb[j] = kmask[b * S_ + j] ? 0.0f : -1e18f;

    {
        const int row = t >> 3, g = t & 7;
        #pragma unroll
        for (int i = 0; i < 2; ++i)
            *reinterpret_cast<uint4*>(&qs[row + i * 32][g * 8]) =
                *reinterpret_cast<const uint4*>(qh + (size_t)(b * S_ + q0 + row + i * 32) * D_ + h * DH_ + g * 8);
    }
    __syncthreads();

    float lsum[4] = {0.f, 0.f, 0.f, 0.f};

    // ---- pass 1: row denominators ----
    for (int kt = 0; kt < S_ / 64; ++kt) {
        const int row = t >> 3, g = t & 7;
        #pragma unroll
        for (int i = 0; i < 2; ++i)
            *reinterpret_cast<uint4*>(&ks[row + i * 32][g * 8]) =
                *reinterpret_cast<const uint4*>(kh + (size_t)(b * S_ + kt * 64 + row + i * 32) * D_ + h * DH_ + g * 8);
        __syncthreads();

        #pragma unroll
        for (int ct = 0; ct < 4; ++ct) {
            f32x4 sa = (f32x4){0.f, 0.f, 0.f, 0.f};
            #pragma unroll
            for (int ks2 = 0; ks2 < 64; ks2 += 32) {
                f16x8 a   = ldsm8(&qs[w * 16 + lr][ks2 + lg * 8]);
                f16x8 bfr = ldsm8(&ks[ct * 16 + lr][ks2 + lg * 8]);
                sa = __builtin_amdgcn_mfma_f32_16x16x32_f16(a, bfr, sa, 0, 0, 0);
            }
            float mbv = mb[kt * 64 + ct * 16 + lr];
            #pragma unroll
            for (int j = 0; j < 4; ++j)
                lsum[j] += __builtin_amdgcn_exp2f(sa[j] + mbv);
        }
        __syncthreads();
    }

    float invl[4];
    #pragma unroll
    for (int j = 0; j < 4; ++j) {
        float s = lsum[j];
        #pragma unroll
        for (int off = 8; off >= 1; off >>= 1)
            s += __shfl_xor(s, off, 64);
        invl[j] = 1.0f / s;
    }
    if (lr == 0) {
        #pragma unroll
        for (int j = 0; j < 4; ++j)
            linv[w * 16 + lg * 4 + j] = invl[j];
    }

    f32x4 oc[4];
    #pragma unroll
    for (int n = 0; n < 4; ++n) oc[n] = (f32x4){0.f, 0.f, 0.f, 0.f};

    const int wrow = t >> 2, wck = t & 3;          // attn-writer assignment
    const size_t arow = ((size_t)(b * H_ + h) * S_ + q0 + wrow) * S_;

    // ---- pass 2: recompute, write attn, accumulate unnormalized ctx ----
    for (int kt = 0; kt < S_ / 64; ++kt) {
        const int row = t >> 3, g = t & 7;
        #pragma unroll
        for (int i = 0; i < 2; ++i) {
            *reinterpret_cast<uint4*>(&ks[row + i * 32][g * 8]) =
                *reinterpret_cast<const uint4*>(kh + (size_t)(b * S_ + kt * 64 + row + i * 32) * D_ + h * DH_ + g * 8);
            *reinterpret_cast<uint4*>(&vt[row + i * 32][g * 8]) =
                *reinterpret_cast<const uint4*>(vtg + ((size_t)(bh * 64 + row + i * 32)) * S_ + kt * 64 + g * 8);
        }
        __syncthreads();

        #pragma unroll
        for (int ct = 0; ct < 4; ++ct) {
            f32x4 sa = (f32x4){0.f, 0.f, 0.f, 0.f};
            #pragma unroll
            for (int ks2 = 0; ks2 < 64; ks2 += 32) {
                f16x8 a   = ldsm8(&qs[w * 16 + lr][ks2 + lg * 8]);
                f16x8 bfr = ldsm8(&ks[ct * 16 + lr][ks2 + lg * 8]);
                sa = __builtin_amdgcn_mfma_f32_16x16x32_f16(a, bfr, sa, 0, 0, 0);
            }
            float mbv = mb[kt * 64 + ct * 16 + lr];
            #pragma unroll
            for (int j = 0; j < 4; ++j)
                ps[w * 16 + lg * 4 + j][ct * 16 + lr] =
                    (f16)__builtin_amdgcn_exp2f(sa[j] + mbv);
        }
        __syncthreads();

        #pragma unroll
        for (int n = 0; n < 4; ++n) {
            #pragma unroll
            for (int ks2 = 0; ks2 < 64; ks2 += 32) {
                f16x8 a   = ldsm8(&ps[w * 16 + lr][ks2 + lg * 8]);
                f16x8 bfr = ldsm8(&vt[n * 16 + lr][ks2 + lg * 8]);
                oc[n] = __builtin_amdgcn_mfma_f32_16x16x32_f16(a, bfr, oc[n], 0, 0, 0);
            }
        }

        {   // coalesced normalized attn write: per quarter-wave 64B contiguous
            float li = linv[wrow];
            #pragma unroll
            for (int r = 0; r < 4; ++r) {
                int c = r * 16 + wck * 4;
                f16x4 v = *reinterpret_cast<const f16x4*>(&ps[wrow][c]);
                float4 o;
                o.x = (float)v[0] * li;
                o.y = (float)v[1] * li;
                o.z = (float)v[2] * li;
                o.w = (float)v[3] * li;
                *reinterpret_cast<float4*>(&attn_out[arow + kt * 64 + c]) = o;
            }
        }
        __syncthreads();
    }

    #pragma unroll
    for (int n = 0; n < 4; ++n) {
        #pragma unroll
        for (int j = 0; j < 4; ++j) {
            int rowq = q0 + w * 16 + lg * 4 + j;
            int d    = n * 16 + lr;
            ch[(size_t)(b * S_ + rowq) * D_ + h * DH_ + d] = (f16)(oc[n][j] * invl[j]);
        }
    }
}

extern "C" void kernel_launch(void* const* d_in, const int* in_sizes, int n_in,
                              void* d_out, int out_size, void* d_ws, size_t ws_size,
                              hipStream_t stream) {
    const float* query = (const float*)d_in[0];
    const float* key   = (const float*)d_in[1];
    const float* value = (const float*)d_in[2];
    const int*   kmask = (const int*)d_in[3];
    const float* Wq = (const float*)d_in[4];
    const float* bq = (const float*)d_in[5];
    const float* Wk = (const float*)d_in[6];
    const float* bk = (const float*)d_in[7];
    const float* Wv = (const float*)d_in[8];
    const float* bv = (const float*)d_in[9];
    const float* Wo = (const float*)d_in[10];
    const float* bo = (const float*)d_in[11];

    float* out  = (float*)d_out;
    float* attn = out + (size_t)B_ * S_ * D_;

    const size_t NE = (size_t)B_ * S_ * D_;
    f16* qh  = (f16*)d_ws;
    f16* kh  = qh + NE;
    f16* vtg = kh + NE;          // per-head transposed V: [(b*16+h)*64+d][s]
    f16* chx = vtg + NE;         // 32 MB of ws total

    dim3 grid(8, 32), blk(256);
    const float qscale = 0.125f * 1.44269504088896340736f;   // (1/sqrt(DH)) * log2(e)

    gemm_bt<0, 1><<<grid, blk, 0, stream>>>((const void*)query, Wq, bq, (void*)qh, qscale);
    gemm_bt<0, 1><<<grid, blk, 0, stream>>>((const void*)key,   Wk, bk, (void*)kh, 1.0f);
    gemm_bt<0, 2><<<grid, blk, 0, stream>>>((const void*)value, Wv, bv, (void*)vtg, 1.0f);

    attn_fused<<<dim3(B_ * H_ * (S_ / 64)), blk, 0, stream>>>(qh, kh, vtg, kmask, attn, chx);

    gemm_bt<1, 0><<<grid, blk, 0, stream>>>((const void*)chx, Wo, bo, (void*)out, 1.0f);
}